// Round 8
// baseline (73.046 us; speedup 1.0000x reference)
//
#include <hip/hip_runtime.h>
#include <hip/hip_cooperative_groups.h>

namespace cg = cooperative_groups;

// (B,C,H,W) = (8,19,512,512), fp32 everywhere.
constexpr int B_ = 8, C_ = 19, H_ = 512, W_ = 512;
constexpr int HW_ = H_ * W_;
constexpr int NB = 512;   // blocks (2/CU on 256 CUs)
constexpr int NT = 512;   // threads (8 waves)

// LDS (floats): [0..14336) tile/stage region; [14336..14848) A-table; [14848..14880) saw
constexpr int LDSF   = 14880;   // 59520 B -> 2 blocks/CU (160 KB LDS)
constexpr int A_OFF  = 14336;
constexpr int SAW_OFF= 14848;

__device__ __forceinline__ int refl(int i, int n) {
    i = (i < 0) ? -i : i;
    return (i >= n) ? (2 * n - 2 - i) : i;
}

__device__ __forceinline__ float v4e(const float4& v, int e) {
    return e == 0 ? v.x : e == 1 ? v.y : e == 2 ? v.z : v.w;
}

// Distance-indexed normalized Gaussian weights in registers.
// ND = K/2+1 distinct values; tap k -> wkr[|k - K/2|].
template<int ND>
__device__ __forceinline__ void gauss_reg(float (&wkr)[ND], float sigma) {
    float s = 0.f;
#pragma unroll
    for (int d = 0; d < ND; ++d) {
        const float t = d / sigma;
        wkr[d] = expf(-0.5f * t * t);
        s += (d ? 2.f : 1.f) * wkr[d];
    }
    const float inv = 1.f / s;
#pragma unroll
    for (int d = 0; d < ND; ++d) wkr[d] *= inv;
}

// Total-contribution weight of input position i under the K=21 reflect blur.
__device__ __forceinline__ float aweight(int i, const float (&wkr)[11]) {
    float a = 0.f;
#pragma unroll
    for (int t = 0; t < 21; ++t) {
        const float k = wkr[(t < 10) ? (10 - t) : (t - 10)];
        const int o = i + 10 - t;
        if (o >= 0 && o < H_) a += k;
        if (i >= 1 && i <= 10 && t <= 10 - i) a += k;
        if (i >= 501 && i <= 510 && t >= 521 - i) a += k;
    }
    return a;
}

// workspace (floats):
//   [0..512)      blockmax (z*32 + htile), z = eye*8 + b
//   [512..1024)   eyesumw  (z*32 + htile): block's sum v*A(h)*A(w)
//   [1024..1536)  esum     (bid)
//   [16384..)     t0: 24 images: z=0..7 w_l, 8..15 w_r, 16..23 einsum out

// ========== Phase A part 1: fused eye pipeline (16-row tile of one eye) ====
// Streaming H-blur 51 -> LDS tile (PADL=28, stride 572, reflected halo)
// -> vectorized W-blur 51 (b128 reads) -> *(1-eyes)(1-bg) -> float4 write.
__device__ __forceinline__ void eye_tile(const float* __restrict__ mp,
                                         float* __restrict__ t0,
                                         float* __restrict__ blockmax,
                                         float* __restrict__ eyesumw,
                                         float* lds, int tid, int vb)
{
    float wkr[26];
    gauss_reg(wkr, 15.f);
    const int z = vb >> 5, hb = (vb & 31) * 16;
    const int eye = z >> 3, b = z & 7;
    const float* sb = mp + ((long)b * C_ + 4 + eye) * HW_;

    float acc[16];
#pragma unroll
    for (int o = 0; o < 16; ++o) acc[o] = 0.f;
#pragma unroll
    for (int j = 0; j < 66; ++j) {                    // rows hb-25 .. hb+40
        const float x = sb[(long)refl(hb - 25 + j, H_) * W_ + tid];
#pragma unroll
        for (int o = 0; o < 16; ++o) {
            const int k = j - o;                      // compile-time after unroll
            if (k >= 0 && k < 51)
                acc[o] = fmaf(x, wkr[(k < 25) ? (25 - k) : (k - 25)], acc[o]);
        }
    }
    float* tile = lds;                                // 16 x 572, s = col + 28
    __syncthreads();                                  // region free of prior use
#pragma unroll
    for (int o = 0; o < 16; ++o) tile[o * 572 + 28 + tid] = acc[o];  // acc dies
    __syncthreads();
    for (int i = tid; i < 800; i += NT) {             // 16 rows x 50 halo cols
        const int r = i / 50, c = i - r * 50;
        float* trow = tile + r * 572;
        if (c < 25) trow[27 - c] = trow[29 + c];          // col -(c+1) <- c+1
        else { const int cc = c - 25; trow[540 + cc] = trow[538 - cc]; } // 512+cc <- 510-cc
    }
    __syncthreads();

    const float* A = lds + A_OFF;
    const int lr = tid >> 7, c0 = (tid & 127) * 4;
    const float Aw[4] = { A[c0], A[c0 + 1], A[c0 + 2], A[c0 + 3] };
    float vmax = 0.f, vsum = 0.f;
#pragma unroll
    for (int pass = 0; pass < 4; ++pass) {
        const int r = pass * 4 + lr;
        const float* trow = tile + r * 572;
        float oo[4] = { 0.f, 0.f, 0.f, 0.f };
#pragma unroll
        for (int m = 0; m < 15; ++m) {
            const float4 v = *(const float4*)(trow + c0 + 4 * m);
#pragma unroll
            for (int e = 0; e < 4; ++e) {
                const int j = 4 * m + e - 28;         // col offset rel c0
                const float x = v4e(v, e);
#pragma unroll
                for (int o = 0; o < 4; ++o) {
                    const int d = j - o;
                    if (d >= -25 && d <= 25)
                        oo[o] = fmaf(x, wkr[d < 0 ? -d : d], oo[o]);
                }
            }
        }
        const long prow = (long)b * C_ * HW_ + (long)(hb + r) * W_ + c0;
        const float4 ey4 = *(const float4*)(mp + prow + (long)(4 + eye) * HW_);
        const float4 bg4 = *(const float4*)(mp + prow);
        float4 vv;
        vv.x = oo[0] * (1.f - ey4.x) * (1.f - bg4.x);
        vv.y = oo[1] * (1.f - ey4.y) * (1.f - bg4.y);
        vv.z = oo[2] * (1.f - ey4.z) * (1.f - bg4.z);
        vv.w = oo[3] * (1.f - ey4.w) * (1.f - bg4.w);
        *(float4*)(t0 + (long)z * HW_ + (long)(hb + r) * W_ + c0) = vv;
        vmax = fmaxf(fmaxf(fmaxf(vv.x, vv.y), fmaxf(vv.z, vv.w)), vmax);
        const float Ah = A[hb + r];
        vsum = fmaf(vv.x, Ah * Aw[0], vsum);
        vsum = fmaf(vv.y, Ah * Aw[1], vsum);
        vsum = fmaf(vv.z, Ah * Aw[2], vsum);
        vsum = fmaf(vv.w, Ah * Aw[3], vsum);
    }
#pragma unroll
    for (int off = 32; off; off >>= 1) {
        vmax = fmaxf(vmax, __shfl_down(vmax, off));
        vsum += __shfl_down(vsum, off);
    }
    __syncthreads();                                  // tile dead -> scratch ok
    if ((tid & 63) == 0) { lds[tid >> 6] = vmax; lds[8 + (tid >> 6)] = vsum; }
    __syncthreads();
    if (tid == 0) {
        float m = lds[0], s = lds[8];
        for (int i = 1; i < 8; ++i) { m = fmaxf(m, lds[i]); s += lds[8 + i]; }
        blockmax[z * 32 + (vb & 31)] = m;
        eyesumw[z * 32 + (vb & 31)] = s;
    }
}

// ========== Phase A part 2: einsum chunk + A-weighted sum ==================
__device__ __forceinline__ void einsum_part(const float* __restrict__ mp,
                                            float* __restrict__ t3,
                                            float* __restrict__ esum,
                                            float* lds, int tid, int bid)
{
    const float* A   = lds + A_OFF;
    const float* saw = lds + SAW_OFF;
    const int b = bid >> 6, chunk = bid & 63;
    float se = 0.f;
#pragma unroll
    for (int q = 0; q < 2; ++q) {
        const int p4 = chunk * 1024 + q * 512 + tid;  // float4 index in batch
        const long p = (long)p4 * 4;
        const int h = (int)(p >> 9), w0 = (int)(p & 511);
        const float* mpb = mp + (long)b * C_ * HW_ + p;
        float4 acc = make_float4(0.f, 0.f, 0.f, 0.f);
#pragma unroll
        for (int c = 0; c < C_; ++c) {
            const float4 v = *(const float4*)(mpb + (long)c * HW_);
            const float a = saw[c];
            acc.x = fmaf(v.x, a, acc.x);
            acc.y = fmaf(v.y, a, acc.y);
            acc.z = fmaf(v.z, a, acc.z);
            acc.w = fmaf(v.w, a, acc.w);
        }
        *(float4*)(t3 + (long)b * HW_ + p) = acc;
        const float dw = acc.x * A[w0] + acc.y * A[w0 + 1]
                       + acc.z * A[w0 + 2] + acc.w * A[w0 + 3];
        se = fmaf(dw, A[h], se);
    }
#pragma unroll
    for (int off = 32; off; off >>= 1) se += __shfl_down(se, off);
    __syncthreads();
    if ((tid & 63) == 0) lds[tid >> 6] = se;
    __syncthreads();
    if (tid == 0) {
        float s = 0.f;
        for (int i = 0; i < 8; ++i) s += lds[i];
        esum[bid] = s;
    }
}

// ========== Phase B: combine + fused 21-tap H+W blur + scaled write ========
__device__ __forceinline__ void phaseB(const float* __restrict__ esw,
                                       const float* __restrict__ t0,
                                       const float* __restrict__ blockmax,
                                       const float* __restrict__ eyesumw,
                                       const float* __restrict__ esum,
                                       float* __restrict__ out,
                                       float* lds, int tid, int vb)
{
    float wkr[11];
    gauss_reg(wkr, 2.f);
    const int b = vb >> 6, tile6 = vb & 63, hb = tile6 * 8;

    // uniform scalar reductions (identical in every thread)
    float mxL = blockmax[b * 32], mxR = blockmax[(8 + b) * 32];
    float SeL = 0.f, SeR = 0.f, Se = 0.f;
    for (int i = 0; i < 32; ++i) {
        mxL = fmaxf(mxL, blockmax[b * 32 + i]);
        mxR = fmaxf(mxR, blockmax[(8 + b) * 32 + i]);
        SeL += eyesumw[b * 32 + i];
        SeR += eyesumw[(8 + b) * 32 + i];
    }
    for (int i = 0; i < 64; ++i) Se += esum[b * 64 + i];
    const float e = esw[0];
    const float sl = e / mxL, sr = e / mxR;
    const float scale = (float)HW_ / (Se + sl * SeL + sr * SeR);

    const float* t1 = t0 + (long)b * HW_;
    const float* t2 = t0 + (long)(8 + b) * HW_;
    const float* t3 = t0 + (long)(16 + b) * HW_;
    float* stage = lds;                                // 28 x 512
    for (int i = tid; i < 28 * 512; i += NT) {
        const int r = i >> 9, c = i & 511;
        const long off = (long)refl(hb - 10 + r, H_) * W_ + c;
        stage[i] = fmaf(t1[off], sl, fmaf(t2[off], sr, t3[off]));
    }
    __syncthreads();

    const int lr = tid >> 7, c0 = (tid & 127) * 4;
    float4 hv[2];
#pragma unroll
    for (int p = 0; p < 2; ++p) {                      // H-pass (vertical taps)
        const int rout = p * 4 + lr;
        float4 a = make_float4(0.f, 0.f, 0.f, 0.f);
#pragma unroll
        for (int k = 0; k < 21; ++k) {
            const float4 v = *(const float4*)(stage + (rout + k) * 512 + c0);
            const float w = wkr[(k < 10) ? (10 - k) : (k - 10)];
            a.x = fmaf(v.x, w, a.x);
            a.y = fmaf(v.y, w, a.y);
            a.z = fmaf(v.z, w, a.z);
            a.w = fmaf(v.w, w, a.w);
        }
        hv[p] = a;
    }
    __syncthreads();                                   // stage dead
    float* st2 = lds;                                  // 8 x 540, s = col + 12
#pragma unroll
    for (int p = 0; p < 2; ++p)
        *(float4*)(st2 + (p * 4 + lr) * 540 + 12 + c0) = hv[p];
    __syncthreads();
    if (tid < 224) {                                   // 8 rows x 28 halo cols
        const int r = tid / 28, c = tid - r * 28;
        float* srow = st2 + r * 540;
        if (c < 12) srow[11 - c] = srow[13 + c];           // col -(c+1) <- c+1
        else { const int cc = c - 12; srow[524 + cc] = srow[522 - cc]; } // 512+cc <- 510-cc
    }
    __syncthreads();
#pragma unroll
    for (int p = 0; p < 2; ++p) {                      // W-pass (vectorized)
        const int r = p * 4 + lr;
        const float* srow = st2 + r * 540;
        float oo[4] = { 0.f, 0.f, 0.f, 0.f };
#pragma unroll
        for (int m = 0; m < 7; ++m) {
            const float4 v = *(const float4*)(srow + c0 + 4 * m);
#pragma unroll
            for (int e = 0; e < 4; ++e) {
                const int j = 4 * m + e - 12;
                const float x = v4e(v, e);
#pragma unroll
                for (int o = 0; o < 4; ++o) {
                    const int d = j - o;
                    if (d >= -10 && d <= 10)
                        oo[o] = fmaf(x, wkr[d < 0 ? -d : d], oo[o]);
                }
            }
        }
        float4 ov4 = make_float4(oo[0] * scale, oo[1] * scale,
                                 oo[2] * scale, oo[3] * scale);
        *(float4*)(out + (long)b * HW_ + (long)(hb + r) * W_ + c0) = ov4;
    }
}

// ===================== cooperative mega kernel (1 grid.sync) ================
__global__ void __launch_bounds__(NT, 4)
mega_kern(const float* __restrict__ mp, const float* __restrict__ aw,
          const float* __restrict__ esw, float* __restrict__ out,
          float* __restrict__ ws)
{
    cg::grid_group grid = cg::this_grid();
    __shared__ __align__(16) float lds[LDSF];
    const int tid = threadIdx.x, bid = blockIdx.x;
    // XCD-chunked swizzle: consecutive vb share an XCD -> halo reads L2-local.
    const int vb = (bid & 7) * 64 + (bid >> 3);
    float* blockmax = ws;
    float* eyesumw  = ws + 512;
    float* esum     = ws + 1024;
    float* t0       = ws + 16384;
    float* t3       = t0 + 16L * HW_;

    {   // A-weight table + area weights (above the tile/stage region)
        float w21[11];
        gauss_reg(w21, 2.f);
        lds[A_OFF + tid] = aweight(tid, w21);
    }
    if (tid < C_) lds[SAW_OFF + tid] = aw[tid];
    __syncthreads();

    // parity-alternated order: mixes compute-heavy and BW-heavy work chip-wide
    if (bid & 1) {
        einsum_part(mp, t3, esum, lds, tid, bid);
        eye_tile(mp, t0, blockmax, eyesumw, lds, tid, vb);
    } else {
        eye_tile(mp, t0, blockmax, eyesumw, lds, tid, vb);
        einsum_part(mp, t3, esum, lds, tid, bid);
    }
    grid.sync();
    phaseB(esw, t0, blockmax, eyesumw, esum, out, lds, tid, vb);
}

// ===================== fallback pipeline (2 kernels) =====================
__global__ void __launch_bounds__(NT)
fb_A_kern(const float* __restrict__ mp, const float* __restrict__ aw,
          float* __restrict__ ws)
{
    __shared__ __align__(16) float lds[LDSF];
    const int tid = threadIdx.x, bid = blockIdx.x;
    const int vb = (bid & 7) * 64 + (bid >> 3);
    float* blockmax = ws;
    float* eyesumw  = ws + 512;
    float* esum     = ws + 1024;
    float* t0       = ws + 16384;
    float* t3       = t0 + 16L * HW_;
    {
        float w21[11];
        gauss_reg(w21, 2.f);
        lds[A_OFF + tid] = aweight(tid, w21);
    }
    if (tid < C_) lds[SAW_OFF + tid] = aw[tid];
    __syncthreads();
    if (bid & 1) {
        einsum_part(mp, t3, esum, lds, tid, bid);
        eye_tile(mp, t0, blockmax, eyesumw, lds, tid, vb);
    } else {
        eye_tile(mp, t0, blockmax, eyesumw, lds, tid, vb);
        einsum_part(mp, t3, esum, lds, tid, bid);
    }
}

__global__ void __launch_bounds__(NT)
fb_B_kern(const float* __restrict__ esw, float* __restrict__ out,
          float* __restrict__ ws)
{
    __shared__ __align__(16) float lds[LDSF];
    const int tid = threadIdx.x, bid = blockIdx.x;
    const int vb = (bid & 7) * 64 + (bid >> 3);
    phaseB(esw, ws + 16384, ws, ws + 512, ws + 1024, out, lds, tid, vb);
}

extern "C" void kernel_launch(void* const* d_in, const int* in_sizes, int n_in,
                              void* d_out, int out_size, void* d_ws, size_t ws_size,
                              hipStream_t stream)
{
    const float* mp  = (const float*)d_in[0];  // (8,19,512,512) f32
    const float* aw  = (const float*)d_in[1];  // (19,) f32
    const float* esw = (const float*)d_in[2];  // (1,) f32
    float* out = (float*)d_out;                // (8,1,512,512) f32
    float* wsf = (float*)d_ws;

    // Deterministic host-side decision (capture-safe: host queries only).
    int coop = 0, nb = 0;
    hipDeviceGetAttribute(&coop, hipDeviceAttributeCooperativeLaunch, 0);
    hipOccupancyMaxActiveBlocksPerMultiprocessor(&nb, (const void*)mega_kern, NT, 0);

    if (coop && nb >= 2) {
        void* args[] = { (void*)&mp, (void*)&aw, (void*)&esw, (void*)&out, (void*)&wsf };
        hipLaunchCooperativeKernel((void*)mega_kern, dim3(NB), dim3(NT), args, 0, stream);
    } else {
        fb_A_kern<<<NB, NT, 0, stream>>>(mp, aw, wsf);
        fb_B_kern<<<NB, NT, 0, stream>>>(esw, out, wsf);
    }
}

// Round 9
// 55.138 us; speedup vs baseline: 1.3248x; 1.3248x over previous
//
#include <hip/hip_runtime.h>
#include <hip/hip_cooperative_groups.h>

namespace cg = cooperative_groups;

// (B,C,H,W) = (8,19,512,512), fp32 everywhere.
constexpr int B_ = 8, C_ = 19, H_ = 512, W_ = 512;
constexpr int HW_ = H_ * W_;
constexpr int NB = 512;   // blocks (2/CU on 256 CUs)
constexpr int NT = 512;   // threads (8 waves)

// LDS (floats): [0..14336) work region; [14336..14848) A-table; [14848..14880) saw
constexpr int LDSF    = 14880;  // 59520 B -> 2 blocks/CU
constexpr int A_OFF   = 14336;
constexpr int SAW_OFF = 14848;
// eye-phase layout inside work region:
//   xh   : 36 x 292  at 0        (downsampled input, half-res)
//   tile2: 10 x 292  at 10512    (H-blurred, with W halo)
//   wh   : 10 x 260  at 0        (overlays dead xh)
constexpr int XH_S = 292, T2_OFF = 10512, T2_S = 292, WH_S = 260;

__device__ __forceinline__ int refl(int i, int n) {
    i = (i < 0) ? -i : i;
    return (i >= n) ? (2 * n - 2 - i) : i;
}

// Distance-indexed normalized Gaussian weights in registers.
// ND = K/2+1 distinct values; tap k -> wkr[|k - K/2|].
template<int ND>
__device__ __forceinline__ void gauss_reg(float (&wkr)[ND], float sigma) {
    float s = 0.f;
#pragma unroll
    for (int d = 0; d < ND; ++d) {
        const float t = d / sigma;
        wkr[d] = expf(-0.5f * t * t);
        s += (d ? 2.f : 1.f) * wkr[d];
    }
    const float inv = 1.f / s;
#pragma unroll
    for (int d = 0; d < ND; ++d) wkr[d] *= inv;
}

// Total-contribution weight of input position i under the K=21 reflect blur.
__device__ __forceinline__ float aweight(int i, const float (&wkr)[11]) {
    float a = 0.f;
#pragma unroll
    for (int t = 0; t < 21; ++t) {
        const float k = wkr[(t < 10) ? (10 - t) : (t - 10)];
        const int o = i + 10 - t;
        if (o >= 0 && o < H_) a += k;
        if (i >= 1 && i <= 10 && t <= 10 - i) a += k;
        if (i >= 501 && i <= 510 && t >= 521 - i) a += k;
    }
    return a;
}

// workspace (floats):
//   [0..512)      blockmax (z*32 + htile), z = eye*8 + b
//   [512..1024)   eyesumw  (z*32 + htile): block's sum v*A(h)*A(w)
//   [1024..1536)  esum     (bid)
//   [16384..)     t0: 24 images: z=0..7 w_l, 8..15 w_r, 16..23 einsum out

// ========== Phase A part 1: HALF-RES eye pipeline (16 full rows/block) =====
// box2 downsample -> 27-tap sigma=7.5 H-blur -> W-blur (all half-res, LDS)
// -> bilinear upsample -> *(1-eyes)(1-bg) -> write v + per-block max/sum.
__device__ __forceinline__ void eye_tile(const float* __restrict__ mp,
                                         float* __restrict__ t0,
                                         float* __restrict__ blockmax,
                                         float* __restrict__ eyesumw,
                                         float* lds, int tid, int vb)
{
    float kh[14];
    gauss_reg(kh, 7.5f);                      // half-res sigma = 15/2
    const int z = vb >> 5, ht = vb & 31;
    const int eye = z >> 3, b = z & 7;
    const int i0 = ht * 8;                    // first half-row of this tile
    const float* sb = mp + ((long)b * C_ + 4 + eye) * HW_;

    __syncthreads();                          // work region free of prior use
    // ---- S1: downsample into xh[36][.]: slot s = global half-row i0-14+s,
    //          col slot jc = global half-col jc-14. Pairs of cells per entry.
    for (int t = 0; t < 10; ++t) {
        const int e = tid + t * NT;
        if (e < 36 * 142) {
            const int s = e / 142, p = e - s * 142;
            const int R = i0 - 14 + s;
            const long r0 = (long)refl(2 * R, H_) * W_;
            const long r1 = (long)refl(2 * R + 1, H_) * W_;
            const int fc = 4 * p - 28;
            float a0, a1;
            if (fc >= 0 && fc + 3 < W_) {
                const float4 u = *(const float4*)(sb + r0 + fc);
                const float4 v = *(const float4*)(sb + r1 + fc);
                a0 = (u.x + u.y + v.x + v.y) * 0.25f;
                a1 = (u.z + u.w + v.z + v.w) * 0.25f;
            } else {
                const int j0 = 2 * p - 14, j1 = j0 + 1;
                a0 = (sb[r0 + refl(2 * j0, W_)] + sb[r0 + refl(2 * j0 + 1, W_)]
                    + sb[r1 + refl(2 * j0, W_)] + sb[r1 + refl(2 * j0 + 1, W_)]) * 0.25f;
                a1 = (sb[r0 + refl(2 * j1, W_)] + sb[r0 + refl(2 * j1 + 1, W_)]
                    + sb[r1 + refl(2 * j1, W_)] + sb[r1 + refl(2 * j1 + 1, W_)]) * 0.25f;
            }
            lds[s * XH_S + 2 * p]     = a0;
            lds[s * XH_S + 2 * p + 1] = a1;
        }
    }
    __syncthreads();
    // ---- S2: H-blur (over rows) -> tile2[10][282], col slot oc = global oc-13
    for (int t = 0; t < 6; ++t) {
        const int e = tid + t * NT;
        if (e < 10 * 282) {
            const int r = e / 282, oc = e - r * 282;
            float acc = 0.f;
#pragma unroll
            for (int dd = 0; dd < 27; ++dd)
                acc = fmaf(lds[(r + dd) * XH_S + oc + 1],
                           kh[(dd < 13) ? (13 - dd) : (dd - 13)], acc);
            lds[T2_OFF + r * T2_S + oc] = acc;
        }
    }
    __syncthreads();
    // ---- S3: W-blur (over cols) -> wh[10][256] at 0 (xh dead; disjoint from T2)
    for (int t = 0; t < 5; ++t) {
        const int e = tid + t * NT;            // 2560 = 5*512 exact
        const int r = e >> 8, c = e & 255;
        float acc = 0.f;
#pragma unroll
        for (int dd = 0; dd < 27; ++dd)
            acc = fmaf(lds[T2_OFF + r * T2_S + c + dd],
                       kh[(dd < 13) ? (13 - dd) : (dd - 13)], acc);
        lds[r * WH_S + c] = acc;
    }
    __syncthreads();
    // ---- S4: bilinear upsample + mask + write + max / A-weighted sum
    const float* A = lds + A_OFF;
    const int c = tid;
    const int j = c >> 1;
    const int jn = (c & 1) ? ((j < 255) ? j + 1 : 255) : ((j > 0) ? j - 1 : 0);
    float cv[10];
#pragma unroll
    for (int s = 0; s < 10; ++s)
        cv[s] = 0.75f * lds[s * WH_S + j] + 0.25f * lds[s * WH_S + jn];
    const float Aw = A[c];
    const long mbase = (long)b * C_ * HW_ + (long)(ht * 16) * W_ + c;
    const float* eyp = mp + mbase + (long)(4 + eye) * HW_;
    const float* bgp = mp + mbase;
    float* db = t0 + (long)z * HW_ + (long)(ht * 16) * W_ + c;
    float vmax = 0.f, vsum = 0.f;
#pragma unroll
    for (int o = 0; o < 16; ++o) {
        const int il = (o >> 1) + 1;           // compile-time local row
        const int i  = i0 + (o >> 1);          // global half-row
        // neighbor row with clamp at image edges (static indices, runtime select)
        const float cvn = (o & 1) ? ((i < 255) ? cv[il + 1] : cv[il])
                                  : ((i > 0)   ? cv[il - 1] : cv[il]);
        const float wv = 0.75f * cv[il] + 0.25f * cvn;
        const float ey = eyp[(long)o * W_], bg = bgp[(long)o * W_];
        const float v = wv * (1.f - ey) * (1.f - bg);
        db[(long)o * W_] = v;
        vmax = fmaxf(vmax, v);
        vsum = fmaf(v, A[ht * 16 + o] * Aw, vsum);
    }
#pragma unroll
    for (int off = 32; off; off >>= 1) {
        vmax = fmaxf(vmax, __shfl_down(vmax, off));
        vsum += __shfl_down(vsum, off);
    }
    __syncthreads();                           // all S4 LDS reads done
    if ((tid & 63) == 0) { lds[tid >> 6] = vmax; lds[8 + (tid >> 6)] = vsum; }
    __syncthreads();
    if (tid == 0) {
        float m = lds[0], s = lds[8];
        for (int i = 1; i < 8; ++i) { m = fmaxf(m, lds[i]); s += lds[8 + i]; }
        blockmax[z * 32 + ht] = m;
        eyesumw[z * 32 + ht] = s;
    }
}

// ========== Phase A part 2: einsum chunk + A-weighted sum ==================
__device__ __forceinline__ void einsum_part(const float* __restrict__ mp,
                                            float* __restrict__ t3,
                                            float* __restrict__ esum,
                                            float* lds, int tid, int bid)
{
    const float* A   = lds + A_OFF;
    const float* saw = lds + SAW_OFF;
    const int b = bid >> 6, chunk = bid & 63;
    float se = 0.f;
#pragma unroll
    for (int q = 0; q < 2; ++q) {
        const int p4 = chunk * 1024 + q * 512 + tid;  // float4 index in batch
        const long p = (long)p4 * 4;
        const int h = (int)(p >> 9), w0 = (int)(p & 511);
        const float* mpb = mp + (long)b * C_ * HW_ + p;
        float4 acc = make_float4(0.f, 0.f, 0.f, 0.f);
#pragma unroll
        for (int c = 0; c < C_; ++c) {
            const float4 v = *(const float4*)(mpb + (long)c * HW_);
            const float a = saw[c];
            acc.x = fmaf(v.x, a, acc.x);
            acc.y = fmaf(v.y, a, acc.y);
            acc.z = fmaf(v.z, a, acc.z);
            acc.w = fmaf(v.w, a, acc.w);
        }
        *(float4*)(t3 + (long)b * HW_ + p) = acc;
        const float dw = acc.x * A[w0] + acc.y * A[w0 + 1]
                       + acc.z * A[w0 + 2] + acc.w * A[w0 + 3];
        se = fmaf(dw, A[h], se);
    }
#pragma unroll
    for (int off = 32; off; off >>= 1) se += __shfl_down(se, off);
    __syncthreads();
    if ((tid & 63) == 0) lds[tid >> 6] = se;
    __syncthreads();
    if (tid == 0) {
        float s = 0.f;
        for (int i = 0; i < 8; ++i) s += lds[i];
        esum[bid] = s;
    }
}

// ========== Phase B: combine + fused 21-tap H+W blur + scaled write ========
// (R7 scalar-b32 version: lane=col mapping is conflict-free)
__device__ __forceinline__ void phaseB(const float* __restrict__ esw,
                                       const float* __restrict__ t0,
                                       const float* __restrict__ blockmax,
                                       const float* __restrict__ eyesumw,
                                       const float* __restrict__ esum,
                                       float* __restrict__ out,
                                       float* lds, int tid, int vb)
{
    float wkr[11];
    gauss_reg(wkr, 2.f);
    const int b = vb >> 6, tile6 = vb & 63, hb = tile6 * 8;

    // uniform scalar reductions (identical in every thread)
    float mxL = blockmax[b * 32], mxR = blockmax[(8 + b) * 32];
    float SeL = 0.f, SeR = 0.f, Se = 0.f;
    for (int i = 0; i < 32; ++i) {
        mxL = fmaxf(mxL, blockmax[b * 32 + i]);
        mxR = fmaxf(mxR, blockmax[(8 + b) * 32 + i]);
        SeL += eyesumw[b * 32 + i];
        SeR += eyesumw[(8 + b) * 32 + i];
    }
    for (int i = 0; i < 64; ++i) Se += esum[b * 64 + i];
    const float e = esw[0];
    const float sl = e / mxL, sr = e / mxR;
    const float scale = (float)HW_ / (Se + sl * SeL + sr * SeR);

    const float* t1 = t0 + (long)b * HW_;
    const float* t2 = t0 + (long)(8 + b) * HW_;
    const float* t3 = t0 + (long)(16 + b) * HW_;
    float* stage = lds;                                // 28 x 512
    for (int i = tid; i < 28 * 512; i += NT) {
        const int r = i >> 9, c = i & 511;
        const long off = (long)refl(hb - 10 + r, H_) * W_ + c;
        stage[i] = fmaf(t1[off], sl, fmaf(t2[off], sr, t3[off]));
    }
    __syncthreads();
    float hv[8];
#pragma unroll
    for (int j = 0; j < 8; ++j) {
        float a = 0.f;
#pragma unroll
        for (int k = 0; k < 21; ++k)
            a = fmaf(stage[(j + k) * 512 + tid], wkr[(k < 10) ? (10 - k) : (k - 10)], a);
        hv[j] = a;
    }
    __syncthreads();
#pragma unroll
    for (int j = 0; j < 8; ++j) stage[j * 512 + tid] = hv[j];   // in-place H rows
    __syncthreads();
#pragma unroll
    for (int j = 0; j < 8; ++j) {
        float a = 0.f;
#pragma unroll
        for (int k = 0; k < 21; ++k)
            a = fmaf(stage[j * 512 + refl(tid - 10 + k, W_)],
                     wkr[(k < 10) ? (10 - k) : (k - 10)], a);
        out[(long)b * HW_ + (long)(hb + j) * W_ + tid] = a * scale;
    }
}

// ===================== cooperative mega kernel (1 grid.sync) ================
__global__ void __launch_bounds__(NT, 4)
mega_kern(const float* __restrict__ mp, const float* __restrict__ aw,
          const float* __restrict__ esw, float* __restrict__ out,
          float* __restrict__ ws)
{
    cg::grid_group grid = cg::this_grid();
    __shared__ __align__(16) float lds[LDSF];
    const int tid = threadIdx.x, bid = blockIdx.x;
    // XCD-chunked swizzle: consecutive vb share an XCD -> halo reads L2-local.
    const int vb = (bid & 7) * 64 + (bid >> 3);
    float* blockmax = ws;
    float* eyesumw  = ws + 512;
    float* esum     = ws + 1024;
    float* t0       = ws + 16384;
    float* t3       = t0 + 16L * HW_;

    {   // A-weight table + area weights (above the work region)
        float w21[11];
        gauss_reg(w21, 2.f);
        lds[A_OFF + tid] = aweight(tid, w21);
    }
    if (tid < C_) lds[SAW_OFF + tid] = aw[tid];
    __syncthreads();

    // parity-alternated order: mixes compute-heavy and BW-heavy work chip-wide
    if (bid & 1) {
        einsum_part(mp, t3, esum, lds, tid, bid);
        eye_tile(mp, t0, blockmax, eyesumw, lds, tid, vb);
    } else {
        eye_tile(mp, t0, blockmax, eyesumw, lds, tid, vb);
        einsum_part(mp, t3, esum, lds, tid, bid);
    }
    grid.sync();
    phaseB(esw, t0, blockmax, eyesumw, esum, out, lds, tid, vb);
}

// ===================== fallback pipeline (2 kernels) =====================
__global__ void __launch_bounds__(NT)
fb_A_kern(const float* __restrict__ mp, const float* __restrict__ aw,
          float* __restrict__ ws)
{
    __shared__ __align__(16) float lds[LDSF];
    const int tid = threadIdx.x, bid = blockIdx.x;
    const int vb = (bid & 7) * 64 + (bid >> 3);
    float* blockmax = ws;
    float* eyesumw  = ws + 512;
    float* esum     = ws + 1024;
    float* t0       = ws + 16384;
    float* t3       = t0 + 16L * HW_;
    {
        float w21[11];
        gauss_reg(w21, 2.f);
        lds[A_OFF + tid] = aweight(tid, w21);
    }
    if (tid < C_) lds[SAW_OFF + tid] = aw[tid];
    __syncthreads();
    if (bid & 1) {
        einsum_part(mp, t3, esum, lds, tid, bid);
        eye_tile(mp, t0, blockmax, eyesumw, lds, tid, vb);
    } else {
        eye_tile(mp, t0, blockmax, eyesumw, lds, tid, vb);
        einsum_part(mp, t3, esum, lds, tid, bid);
    }
}

__global__ void __launch_bounds__(NT)
fb_B_kern(const float* __restrict__ esw, float* __restrict__ out,
          float* __restrict__ ws)
{
    __shared__ __align__(16) float lds[LDSF];
    const int tid = threadIdx.x, bid = blockIdx.x;
    const int vb = (bid & 7) * 64 + (bid >> 3);
    phaseB(esw, ws + 16384, ws, ws + 512, ws + 1024, out, lds, tid, vb);
}

extern "C" void kernel_launch(void* const* d_in, const int* in_sizes, int n_in,
                              void* d_out, int out_size, void* d_ws, size_t ws_size,
                              hipStream_t stream)
{
    const float* mp  = (const float*)d_in[0];  // (8,19,512,512) f32
    const float* aw  = (const float*)d_in[1];  // (19,) f32
    const float* esw = (const float*)d_in[2];  // (1,) f32
    float* out = (float*)d_out;                // (8,1,512,512) f32
    float* wsf = (float*)d_ws;

    // Deterministic host-side decision (capture-safe: host queries only).
    int coop = 0, nb = 0;
    hipDeviceGetAttribute(&coop, hipDeviceAttributeCooperativeLaunch, 0);
    hipOccupancyMaxActiveBlocksPerMultiprocessor(&nb, (const void*)mega_kern, NT, 0);

    if (coop && nb >= 2) {
        void* args[] = { (void*)&mp, (void*)&aw, (void*)&esw, (void*)&out, (void*)&wsf };
        hipLaunchCooperativeKernel((void*)mega_kern, dim3(NB), dim3(NT), args, 0, stream);
    } else {
        fb_A_kern<<<NB, NT, 0, stream>>>(mp, aw, wsf);
        fb_B_kern<<<NB, NT, 0, stream>>>(esw, out, wsf);
    }
}

// Round 10
// 51.511 us; speedup vs baseline: 1.4181x; 1.0704x over previous
//
#include <hip/hip_runtime.h>
#include <hip/hip_cooperative_groups.h>

namespace cg = cooperative_groups;

// (B,C,H,W) = (8,19,512,512), fp32 everywhere.
constexpr int B_ = 8, C_ = 19, H_ = 512, W_ = 512;
constexpr int HW_ = H_ * W_;
constexpr int NB = 512;   // blocks (2/CU on 256 CUs)
constexpr int NT = 512;   // threads (8 waves)

// LDS (floats): [0..14336) work region; [14336..14848) A-table; [14848..14880) saw
constexpr int LDSF    = 14880;  // 59520 B -> 2 blocks/CU
constexpr int A_OFF   = 14336;
constexpr int SAW_OFF = 14848;
// eye-phase layout: xh 36x292 at 0; tile2 10x292 at 10512; wh 10x260 at 0 (over dead xh)
constexpr int XH_S = 292, T2_OFF = 10512, T2_S = 292, WH_S = 260;
// phase-B layout: st 8x540 at 0 (H-blur result + 12/16-col halos)
constexpr int ST_S = 540;

__device__ __forceinline__ int refl(int i, int n) {
    i = (i < 0) ? -i : i;
    return (i >= n) ? (2 * n - 2 - i) : i;
}

// Distance-indexed normalized Gaussian weights in registers.
template<int ND>
__device__ __forceinline__ void gauss_reg(float (&wkr)[ND], float sigma) {
    float s = 0.f;
#pragma unroll
    for (int d = 0; d < ND; ++d) {
        const float t = d / sigma;
        wkr[d] = expf(-0.5f * t * t);
        s += (d ? 2.f : 1.f) * wkr[d];
    }
    const float inv = 1.f / s;
#pragma unroll
    for (int d = 0; d < ND; ++d) wkr[d] *= inv;
}

// Total-contribution weight of input position i under the K=21 reflect blur.
__device__ __forceinline__ float aweight(int i, const float (&wkr)[11]) {
    float a = 0.f;
#pragma unroll
    for (int t = 0; t < 21; ++t) {
        const float k = wkr[(t < 10) ? (10 - t) : (t - 10)];
        const int o = i + 10 - t;
        if (o >= 0 && o < H_) a += k;
        if (i >= 1 && i <= 10 && t <= 10 - i) a += k;
        if (i >= 501 && i <= 510 && t >= 521 - i) a += k;
    }
    return a;
}

// workspace (floats):
//   [0..512)      blockmax (z*32 + ht), z = eye*8 + b
//   [512..1024)   eyesumw  (z*32 + ht)
//   [1024..1536)  esum     (vb = b*64 + chunk)
//   [16384..)     t0: 24 images (0..7 w_l, 8..15 w_r, 16..23 einsum out)
// vb decode everywhere: b = vb>>6 (so all of batch b lives on XCD b).

// ========== Phase A part 1: HALF-RES eye pipeline ==========
__device__ __forceinline__ void eye_tile(const float* __restrict__ mp,
                                         float* __restrict__ t0,
                                         float* __restrict__ blockmax,
                                         float* __restrict__ eyesumw,
                                         float* lds, int tid, int vb)
{
    float kh[14];
    gauss_reg(kh, 7.5f);                      // half-res sigma = 15/2
    const int b = vb >> 6, eye = (vb >> 5) & 1, ht = vb & 31;
    const int z = eye * 8 + b;
    const int i0 = ht * 8;                    // first half-row of this tile
    const float* sb = mp + ((long)b * C_ + 4 + eye) * HW_;

    __syncthreads();                          // work region free of prior use
    // ---- S1: box2 downsample into xh[36][292] (slot s = half-row i0-14+s)
    for (int t = 0; t < 10; ++t) {
        const int e = tid + t * NT;
        if (e < 36 * 142) {
            const int s = e / 142, p = e - s * 142;
            const int R = i0 - 14 + s;
            const long r0 = (long)refl(2 * R, H_) * W_;
            const long r1 = (long)refl(2 * R + 1, H_) * W_;
            const int fc = 4 * p - 28;
            float a0, a1;
            if (fc >= 0 && fc + 3 < W_) {
                const float4 u = *(const float4*)(sb + r0 + fc);
                const float4 v = *(const float4*)(sb + r1 + fc);
                a0 = (u.x + u.y + v.x + v.y) * 0.25f;
                a1 = (u.z + u.w + v.z + v.w) * 0.25f;
            } else {
                const int j0 = 2 * p - 14, j1 = j0 + 1;
                a0 = (sb[r0 + refl(2 * j0, W_)] + sb[r0 + refl(2 * j0 + 1, W_)]
                    + sb[r1 + refl(2 * j0, W_)] + sb[r1 + refl(2 * j0 + 1, W_)]) * 0.25f;
                a1 = (sb[r0 + refl(2 * j1, W_)] + sb[r0 + refl(2 * j1 + 1, W_)]
                    + sb[r1 + refl(2 * j1, W_)] + sb[r1 + refl(2 * j1 + 1, W_)]) * 0.25f;
            }
            *(float2*)(lds + s * XH_S + 2 * p) = make_float2(a0, a1);
        }
    }
    __syncthreads();
    // ---- S2: H-blur via register sliding window (thread = col slot, 10 outs)
    if (tid < 282) {
        float w2[36];
#pragma unroll
        for (int s = 0; s < 36; ++s) w2[s] = lds[s * XH_S + tid + 1];
#pragma unroll
        for (int r = 0; r < 10; ++r) {
            float a = 0.f;
#pragma unroll
            for (int dd = 0; dd < 27; ++dd)
                a = fmaf(w2[r + dd], kh[(dd < 13) ? (13 - dd) : (dd - 13)], a);
            lds[T2_OFF + r * T2_S + tid] = a;
        }
    }
    __syncthreads();
    // ---- S3: W-blur via lane-linear b128 windows -> wh[10][260] at 0
    {
        const int r = tid >> 6, g = tid & 63;
        {
            const float* trow = lds + T2_OFF + r * T2_S + 4 * g;
            float wn[32];
#pragma unroll
            for (int m = 0; m < 8; ++m) {
                const float4 v = *(const float4*)(trow + 4 * m);
                wn[4*m] = v.x; wn[4*m+1] = v.y; wn[4*m+2] = v.z; wn[4*m+3] = v.w;
            }
            float o4[4];
#pragma unroll
            for (int o = 0; o < 4; ++o) {
                float a = 0.f;
#pragma unroll
                for (int dd = 0; dd < 27; ++dd)
                    a = fmaf(wn[o + dd], kh[(dd < 13) ? (13 - dd) : (dd - 13)], a);
                o4[o] = a;
            }
            *(float4*)(lds + r * WH_S + 4 * g) = make_float4(o4[0], o4[1], o4[2], o4[3]);
        }
        if (tid < 128) {                      // rows 8,9
            const int r2 = 8 + (tid >> 6);
            const float* trow = lds + T2_OFF + r2 * T2_S + 4 * g;
            float wn[32];
#pragma unroll
            for (int m = 0; m < 8; ++m) {
                const float4 v = *(const float4*)(trow + 4 * m);
                wn[4*m] = v.x; wn[4*m+1] = v.y; wn[4*m+2] = v.z; wn[4*m+3] = v.w;
            }
            float o4[4];
#pragma unroll
            for (int o = 0; o < 4; ++o) {
                float a = 0.f;
#pragma unroll
                for (int dd = 0; dd < 27; ++dd)
                    a = fmaf(wn[o + dd], kh[(dd < 13) ? (13 - dd) : (dd - 13)], a);
                o4[o] = a;
            }
            *(float4*)(lds + r2 * WH_S + 4 * g) = make_float4(o4[0], o4[1], o4[2], o4[3]);
        }
    }
    __syncthreads();
    // ---- S4: bilinear upsample + mask + write + max / A-weighted sum
    const float* A = lds + A_OFF;
    const int c = tid;
    const int j = c >> 1;
    const int jn = (c & 1) ? ((j < 255) ? j + 1 : 255) : ((j > 0) ? j - 1 : 0);
    float cv[10];
#pragma unroll
    for (int s = 0; s < 10; ++s)
        cv[s] = 0.75f * lds[s * WH_S + j] + 0.25f * lds[s * WH_S + jn];
    const float Aw = A[c];
    const long mbase = (long)b * C_ * HW_ + (long)(ht * 16) * W_ + c;
    const float* eyp = mp + mbase + (long)(4 + eye) * HW_;
    const float* bgp = mp + mbase;
    float* db = t0 + (long)z * HW_ + (long)(ht * 16) * W_ + c;
    float vmax = 0.f, vsum = 0.f;
#pragma unroll
    for (int o = 0; o < 16; ++o) {
        const int il = (o >> 1) + 1;
        const int i  = i0 + (o >> 1);
        const float cvn = (o & 1) ? ((i < 255) ? cv[il + 1] : cv[il])
                                  : ((i > 0)   ? cv[il - 1] : cv[il]);
        const float wv = 0.75f * cv[il] + 0.25f * cvn;
        const float ey = eyp[(long)o * W_], bg = bgp[(long)o * W_];
        const float v = wv * (1.f - ey) * (1.f - bg);
        db[(long)o * W_] = v;
        vmax = fmaxf(vmax, v);
        vsum = fmaf(v, A[ht * 16 + o] * Aw, vsum);
    }
#pragma unroll
    for (int off = 32; off; off >>= 1) {
        vmax = fmaxf(vmax, __shfl_down(vmax, off));
        vsum += __shfl_down(vsum, off);
    }
    __syncthreads();                           // all S4 LDS reads done
    if ((tid & 63) == 0) { lds[tid >> 6] = vmax; lds[8 + (tid >> 6)] = vsum; }
    __syncthreads();
    if (tid == 0) {
        float m = lds[0], s = lds[8];
        for (int i = 1; i < 8; ++i) { m = fmaxf(m, lds[i]); s += lds[8 + i]; }
        blockmax[z * 32 + ht] = m;
        eyesumw[z * 32 + ht] = s;
    }
}

// ========== Phase A part 2: einsum chunk + A-weighted sum (vb-keyed) =======
__device__ __forceinline__ void einsum_part(const float* __restrict__ mp,
                                            float* __restrict__ t3,
                                            float* __restrict__ esum,
                                            float* lds, int tid, int vb)
{
    const float* A   = lds + A_OFF;
    const float* saw = lds + SAW_OFF;
    const int b = vb >> 6, chunk = vb & 63;
    float se = 0.f;
#pragma unroll
    for (int q = 0; q < 2; ++q) {
        const int p4 = chunk * 1024 + q * 512 + tid;  // float4 index in batch
        const long p = (long)p4 * 4;
        const int h = (int)(p >> 9), w0 = (int)(p & 511);
        const float* mpb = mp + (long)b * C_ * HW_ + p;
        float4 acc = make_float4(0.f, 0.f, 0.f, 0.f);
#pragma unroll
        for (int c = 0; c < C_; ++c) {
            const float4 v = *(const float4*)(mpb + (long)c * HW_);
            const float a = saw[c];
            acc.x = fmaf(v.x, a, acc.x);
            acc.y = fmaf(v.y, a, acc.y);
            acc.z = fmaf(v.z, a, acc.z);
            acc.w = fmaf(v.w, a, acc.w);
        }
        *(float4*)(t3 + (long)b * HW_ + p) = acc;
        const float4 a4 = *(const float4*)(A + w0);   // aligned, lane-linear
        se = fmaf(acc.x * a4.x + acc.y * a4.y + acc.z * a4.z + acc.w * a4.w,
                  A[h], se);
    }
#pragma unroll
    for (int off = 32; off; off >>= 1) se += __shfl_down(se, off);
    __syncthreads();
    if ((tid & 63) == 0) lds[tid >> 6] = se;
    __syncthreads();
    if (tid == 0) {
        float s = 0.f;
        for (int i = 0; i < 8; ++i) s += lds[i];
        esum[vb] = s;
    }
}

// ========== Phase B: combine + 21-tap blur, register windows ===============
__device__ __forceinline__ void phaseB(const float* __restrict__ esw,
                                       const float* __restrict__ t0,
                                       const float* __restrict__ blockmax,
                                       const float* __restrict__ eyesumw,
                                       const float* __restrict__ esum,
                                       float* __restrict__ out,
                                       float* lds, int tid, int vb)
{
    float wkr[11];
    gauss_reg(wkr, 2.f);
    const int b = vb >> 6, tile6 = vb & 63, hb = tile6 * 8;

    // uniform scalar reductions (identical in every thread)
    float mxL = blockmax[b * 32], mxR = blockmax[(8 + b) * 32];
    float SeL = 0.f, SeR = 0.f, Se = 0.f;
    for (int i = 0; i < 32; ++i) {
        mxL = fmaxf(mxL, blockmax[b * 32 + i]);
        mxR = fmaxf(mxR, blockmax[(8 + b) * 32 + i]);
        SeL += eyesumw[b * 32 + i];
        SeR += eyesumw[(8 + b) * 32 + i];
    }
    for (int i = 0; i < 64; ++i) Se += esum[b * 64 + i];
    const float e = esw[0];
    const float sl = e / mxL, sr = e / mxR;
    const float scale = (float)HW_ / (Se + sl * SeL + sr * SeR);

    const float* t1 = t0 + (long)b * HW_;
    const float* t2 = t0 + (long)(8 + b) * HW_;
    const float* t3 = t0 + (long)(16 + b) * HW_;

    // H-pass: thread = col, combine+window straight from global (no LDS stage)
    const int c = tid;
    float win[28];
#pragma unroll
    for (int i = 0; i < 28; ++i) {
        const long off = (long)refl(hb - 10 + i, H_) * W_ + c;
        win[i] = fmaf(t1[off], sl, fmaf(t2[off], sr, t3[off]));
    }
    float hv[8];
#pragma unroll
    for (int j = 0; j < 8; ++j) {
        float a = 0.f;
#pragma unroll
        for (int k = 0; k < 21; ++k)
            a = fmaf(win[j + k], wkr[(k < 10) ? (10 - k) : (k - 10)], a);
        hv[j] = a;
    }
    float* st = lds;                                   // 8 x 540, col x at 12+x
#pragma unroll
    for (int j = 0; j < 8; ++j) st[j * ST_S + 12 + c] = hv[j];
    __syncthreads();
    if (tid < 224) {                                   // 8 rows x 28 halo cols
        const int r = tid / 28, q = tid - r * 28;
        float* srow = st + r * ST_S;
        if (q < 12) srow[11 - q] = srow[13 + q];               // col -(q+1) <- q+1
        else { const int cc = q - 12; srow[524 + cc] = srow[522 - cc]; } // 512+cc <- 510-cc
    }
    __syncthreads();
    // W-pass: wave = row, lane = 8-col group; b128 window reads
    const int r = tid >> 6, g = tid & 63, c0 = g * 8;
    const float* srow = st + r * ST_S;                 // col x at srow[12+x]
    float wn[32];                                      // cols c0-12 .. c0+19
#pragma unroll
    for (int m = 0; m < 8; ++m) {
        const float4 v = *(const float4*)(srow + c0 + 4 * m);
        wn[4*m] = v.x; wn[4*m+1] = v.y; wn[4*m+2] = v.z; wn[4*m+3] = v.w;
    }
    float oo[8];
#pragma unroll
    for (int o = 0; o < 8; ++o) {                      // out col c0+o: wn[o+2..o+22]
        float a = 0.f;
#pragma unroll
        for (int k = 0; k < 21; ++k)
            a = fmaf(wn[o + 2 + k], wkr[(k < 10) ? (10 - k) : (k - 10)], a);
        oo[o] = a * scale;
    }
    float* orow = out + (long)b * HW_ + (long)(hb + r) * W_ + c0;
    *(float4*)(orow)     = make_float4(oo[0], oo[1], oo[2], oo[3]);
    *(float4*)(orow + 4) = make_float4(oo[4], oo[5], oo[6], oo[7]);
}

// ===================== cooperative mega kernel (1 grid.sync) ================
__global__ void __launch_bounds__(NT, 4)
mega_kern(const float* __restrict__ mp, const float* __restrict__ aw,
          const float* __restrict__ esw, float* __restrict__ out,
          float* __restrict__ ws)
{
    cg::grid_group grid = cg::this_grid();
    __shared__ __align__(16) float lds[LDSF];
    const int tid = threadIdx.x, bid = blockIdx.x;
    // XCD swizzle with vb>>6 = batch: all of batch b's work lands on XCD b.
    const int vb = (bid & 7) * 64 + (bid >> 3);
    float* blockmax = ws;
    float* eyesumw  = ws + 512;
    float* esum     = ws + 1024;
    float* t0       = ws + 16384;
    float* t3       = t0 + 16L * HW_;

    {   // A-weight table + area weights (above the work region)
        float w21[11];
        gauss_reg(w21, 2.f);
        lds[A_OFF + tid] = aweight(tid, w21);
    }
    if (tid < C_) lds[SAW_OFF + tid] = aw[tid];
    __syncthreads();

    // parity-alternated order: mixes compute-heavy and BW-heavy work chip-wide
    if (bid & 1) {
        einsum_part(mp, t3, esum, lds, tid, vb);
        eye_tile(mp, t0, blockmax, eyesumw, lds, tid, vb);
    } else {
        eye_tile(mp, t0, blockmax, eyesumw, lds, tid, vb);
        einsum_part(mp, t3, esum, lds, tid, vb);
    }
    grid.sync();
    phaseB(esw, t0, blockmax, eyesumw, esum, out, lds, tid, vb);
}

// ===================== fallback pipeline (2 kernels) =====================
__global__ void __launch_bounds__(NT)
fb_A_kern(const float* __restrict__ mp, const float* __restrict__ aw,
          float* __restrict__ ws)
{
    __shared__ __align__(16) float lds[LDSF];
    const int tid = threadIdx.x, bid = blockIdx.x;
    const int vb = (bid & 7) * 64 + (bid >> 3);
    float* blockmax = ws;
    float* eyesumw  = ws + 512;
    float* esum     = ws + 1024;
    float* t0       = ws + 16384;
    float* t3       = t0 + 16L * HW_;
    {
        float w21[11];
        gauss_reg(w21, 2.f);
        lds[A_OFF + tid] = aweight(tid, w21);
    }
    if (tid < C_) lds[SAW_OFF + tid] = aw[tid];
    __syncthreads();
    if (bid & 1) {
        einsum_part(mp, t3, esum, lds, tid, vb);
        eye_tile(mp, t0, blockmax, eyesumw, lds, tid, vb);
    } else {
        eye_tile(mp, t0, blockmax, eyesumw, lds, tid, vb);
        einsum_part(mp, t3, esum, lds, tid, vb);
    }
}

__global__ void __launch_bounds__(NT)
fb_B_kern(const float* __restrict__ esw, float* __restrict__ out,
          float* __restrict__ ws)
{
    __shared__ __align__(16) float lds[LDSF];
    const int tid = threadIdx.x, bid = blockIdx.x;
    const int vb = (bid & 7) * 64 + (bid >> 3);
    phaseB(esw, ws + 16384, ws, ws + 512, ws + 1024, out, lds, tid, vb);
}

extern "C" void kernel_launch(void* const* d_in, const int* in_sizes, int n_in,
                              void* d_out, int out_size, void* d_ws, size_t ws_size,
                              hipStream_t stream)
{
    const float* mp  = (const float*)d_in[0];  // (8,19,512,512) f32
    const float* aw  = (const float*)d_in[1];  // (19,) f32
    const float* esw = (const float*)d_in[2];  // (1,) f32
    float* out = (float*)d_out;                // (8,1,512,512) f32
    float* wsf = (float*)d_ws;

    // Deterministic host-side decision (capture-safe: host queries only).
    int coop = 0, nb = 0;
    hipDeviceGetAttribute(&coop, hipDeviceAttributeCooperativeLaunch, 0);
    hipOccupancyMaxActiveBlocksPerMultiprocessor(&nb, (const void*)mega_kern, NT, 0);

    if (coop && nb >= 2) {
        void* args[] = { (void*)&mp, (void*)&aw, (void*)&esw, (void*)&out, (void*)&wsf };
        hipLaunchCooperativeKernel((void*)mega_kern, dim3(NB), dim3(NT), args, 0, stream);
    } else {
        fb_A_kern<<<NB, NT, 0, stream>>>(mp, aw, wsf);
        fb_B_kern<<<NB, NT, 0, stream>>>(esw, out, wsf);
    }
}